// Round 3
// baseline (1951.685 us; speedup 1.0000x reference)
//
#include <hip/hip_runtime.h>
#include <math.h>

// Problem constants (fixed by setup_inputs)
#define E_N 100000
#define D_N 300
#define R_N 1000
#define T_N 10000
#define K_N 25
#define DP  320      // padded D (multiple of 32)
#define KD  960      // padded 3D

typedef __attribute__((ext_vector_type(8))) short bf16x8;
typedef __attribute__((ext_vector_type(4))) float f32x4;

__device__ __forceinline__ float bf2f(unsigned short h){
  union{ unsigned int u; float f; } c; c.u = ((unsigned int)h)<<16; return c.f;
}
__device__ __forceinline__ unsigned short f2bf(float f){
  union{ float f; unsigned int u; } c; c.f = f;
  unsigned int u = c.u + 0x7FFFu + ((c.u>>16)&1u);   // RNE
  return (unsigned short)(u>>16);
}
__device__ __forceinline__ unsigned int pack2(float lo, float hi){
  return ((unsigned int)f2bf(hi)<<16) | f2bf(lo);
}

// ---------------- workspace layout (bytes) ----------------
static constexpr size_t OFF_EMBB  = 0;                         // E*320*2 = 64MB (emb/h/hg1/node, in place)
static constexpr size_t OFF_HWB   = 64000000;                  // 64MB (h@W)
static constexpr size_t OFF_GCNB  = OFF_HWB + 64000000;        // 64MB
static constexpr size_t OFF_RFWD  = 192000000;                 // R*640*2 bf16 = 1.28MB
static constexpr size_t OFF_WTKG  = OFF_RFWD + 2400000;
static constexpr size_t OFF_WTW1  = OFF_WTKG + 204800;
static constexpr size_t OFF_WTW2  = OFF_WTW1 + 204800;
static constexpr size_t OFF_WTDN  = OFF_WTW2 + 204800;         // [320,960] bf16 transposed
static constexpr size_t OFF_BIASP = OFF_WTDN + 614400;
static constexpr size_t OFF_BGP   = OFF_BIASP + 1280;
static constexpr size_t OFF_PTRHR = OFF_BGP + 1280;
static constexpr size_t OFF_PTRTR = OFF_PTRHR + 4096;
static constexpr size_t OFF_PTRER = OFF_PTRTR + 4096;
static constexpr size_t OFF_PTRADJ= OFF_PTRER + 400896;
static constexpr size_t OFF_CURHR = OFF_PTRADJ + 400896;       // cursors contiguous: 1 memset
static constexpr size_t OFF_CURTR = OFF_CURHR + 4096;
static constexpr size_t OFF_CURER = OFF_CURTR + 4096;
static constexpr size_t OFF_CURADJ= OFF_CURER + 400896;
static constexpr size_t SZ_CURALL = 4096+4096+400896+400896;
static constexpr size_t OFF_SCHR  = OFF_CURADJ + 400896;
static constexpr size_t OFF_SVHR  = OFF_SCHR + 1200000;
static constexpr size_t OFF_SCTR  = OFF_SVHR + 1200000;
static constexpr size_t OFF_SVTR  = OFF_SCTR + 1200000;
static constexpr size_t OFF_SCER  = OFF_SVTR + 1200000;
static constexpr size_t OFF_SVER  = OFF_SCER + 1200000;
static constexpr size_t OFF_SCADJ = OFF_SVER + 1200000;
static constexpr size_t OFF_SVADJ = OFF_SCADJ + 2400000;
static constexpr size_t OFF_DM    = OFF_SVADJ + 2400000;
static constexpr size_t OFF_PART  = OFF_DM + 40000;
static constexpr size_t OFF_BSUM  = OFF_PART + 40000;          // 256 ints

// ---------------- weight prep ----------------
__global__ void k_prep_sq(const float* kg, const float* w1, const float* w2,
                          unsigned short* wtKG, unsigned short* wtW1, unsigned short* wtW2){
  int n = blockIdx.x, which = blockIdx.y, k = threadIdx.x;
  const float* src = which==0 ? kg : (which==1 ? w1 : w2);
  unsigned short* dst = which==0 ? wtKG : (which==1 ? wtW1 : wtW2);
  float v = (n < D_N && k < D_N) ? src[k*D_N + n] : 0.f;
  dst[(size_t)n*DP + k] = f2bf(v);
}

// DenseP_t[n][k]: k<300 -> Dense[k][n]; 320<=k<920 -> Dense[k-20][n]; else 0
__global__ void k_prep_dense(const float* dn, unsigned short* wt){
  int n = blockIdx.x, t = threadIdx.x;
  for(int k=t; k<KD; k+=320){
    int ko = (k < D_N) ? k : ((k >= DP && k < 920) ? k-20 : -1);
    float v = (n < D_N && ko >= 0) ? dn[(size_t)ko*D_N + n] : 0.f;
    wt[(size_t)n*KD + k] = f2bf(v);
  }
}

__global__ void k_prep_bias(const float* bias, const float* bg, float* biasP, float* bgP){
  int t = threadIdx.x;
  biasP[t] = (t < D_N) ? bias[t] : 0.f;
  bgP[t]   = (t < D_N) ? bg[t]   : 0.f;
}

// ---------------- emb normalize -> bf16 padded (wave-per-row, float4) ----------------
__global__ __launch_bounds__(256) void k_normalize(const float* __restrict__ w,
                                                   unsigned short* __restrict__ embb){
  int wv = threadIdx.x >> 6, lane = threadIdx.x & 63;
  int e = blockIdx.x*4 + wv;                      // grid = E/4
  const float4* row = (const float4*)(w + (size_t)e*D_N);   // 1200B rows, 16B aligned
  float4 x0 = row[lane];
  float4 x1 = make_float4(0.f,0.f,0.f,0.f);
  if(lane < 11) x1 = row[64 + lane];              // floats 256..299
  float s = x0.x*x0.x + x0.y*x0.y + x0.z*x0.z + x0.w*x0.w
          + x1.x*x1.x + x1.y*x1.y + x1.z*x1.z + x1.w*x1.w;
  #pragma unroll
  for(int off=32; off; off>>=1) s += __shfl_xor(s, off);
  float rn = rsqrtf(s);
  unsigned short* orow = embb + (size_t)e*DP;
  uint2 o0; o0.x = pack2(x0.x*rn, x0.y*rn); o0.y = pack2(x0.z*rn, x0.w*rn);
  *(uint2*)(orow + lane*4) = o0;
  if(lane < 16){
    uint2 o1 = make_uint2(0u,0u);
    if(lane < 11){ o1.x = pack2(x1.x*rn, x1.y*rn); o1.y = pack2(x1.z*rn, x1.w*rn); }
    *(uint2*)(orow + 256 + lane*4) = o1;          // cols 256..319 (incl. zero pad)
  }
}

// ---------------- CSR build (counting sort) ----------------
__global__ void k_count(const int* hr, const int* tr, const int* er, const int* ad,
                        int* cHR, int* cTR, int* cER, int* cAD){
  int i = blockIdx.x*256 + threadIdx.x;
  if(i < 300000)       atomicAdd(&cHR[hr[i]], 1);
  else if(i < 600000)  atomicAdd(&cTR[tr[i-300000]], 1);
  else if(i < 900000)  atomicAdd(&cER[er[i-600000]], 1);
  else if(i < 1500000) atomicAdd(&cAD[ad[i-900000]], 1);
}

__global__ void k_scan_small(int* cHR, int* cTR, int* pHR, int* pTR){
  __shared__ int s[1024];
  int t = threadIdx.x;
  for(int w=0; w<2; w++){
    int* cnt = w ? cTR : cHR; int* ptr = w ? pTR : pHR;
    int c = (t < R_N) ? cnt[t] : 0;
    s[t] = c; __syncthreads();
    for(int off=1; off<1024; off<<=1){
      int v = (t>=off) ? s[t-off] : 0; __syncthreads();
      s[t] += v; __syncthreads();
    }
    int excl = s[t] - c;
    if(t < R_N){ ptr[t] = excl; cnt[t] = excl; }
    if(t == R_N-1) ptr[R_N] = s[t];
    __syncthreads();
  }
}

__global__ void k_scan_part(const int* cER, const int* cAD, int* pER, int* pAD, int* bsum){
  int which = blockIdx.y;
  const int* cnt = which ? cAD : cER;
  int* ptr = which ? pAD : pER;
  __shared__ int s[1024];
  int g = blockIdx.x, t = threadIdx.x, i = g*1024 + t;
  int c = (i < E_N) ? cnt[i] : 0;
  s[t] = c; __syncthreads();
  for(int off=1; off<1024; off<<=1){
    int v = (t>=off) ? s[t-off] : 0; __syncthreads();
    s[t] += v; __syncthreads();
  }
  if(i < E_N) ptr[i] = s[t] - c;
  if(t == 1023) bsum[which*128 + g] = s[1023];
}

__global__ void k_scan_mid(int* bsum, int* pER, int* pAD){
  __shared__ int s[128];
  int t = threadIdx.x;
  for(int w=0; w<2; w++){
    int v = (t < 98) ? bsum[w*128 + t] : 0;
    s[t] = v; __syncthreads();
    for(int off=1; off<128; off<<=1){
      int u = (t>=off) ? s[t-off] : 0; __syncthreads();
      s[t] += u; __syncthreads();
    }
    if(t < 98) bsum[w*128 + t] = s[t] - v;
    if(t == 97){ int* p = w ? pAD : pER; p[E_N] = s[97]; }
    __syncthreads();
  }
}

__global__ void k_scan_add(const int* bsum, int* pER, int* pAD, int* curER, int* curAD){
  int which = blockIdx.y;
  int* ptr = which ? pAD : pER;
  int* cur = which ? curAD : curER;
  int g = blockIdx.x, i = g*1024 + threadIdx.x;
  if(i < E_N){ int v = ptr[i] + bsum[which*128 + g]; ptr[i] = v; cur[i] = v; }
}

__global__ void k_scatter(const int* hr_r, const int* hr_c, const float* hr_v,
                          const int* tr_r, const int* tr_c, const float* tr_v,
                          const int* er_r, const int* er_c, const float* er_v,
                          const int* ad_r, const int* ad_c, const float* ad_v,
                          int* cHR, int* cTR, int* cER, int* cAD,
                          int* scHR, float* svHR, int* scTR, float* svTR,
                          int* scER, float* svER, int* scAD, float* svAD){
  int i = blockIdx.x*256 + threadIdx.x;
  if(i < 300000){ int p=atomicAdd(&cHR[hr_r[i]],1); scHR[p]=hr_c[i]; svHR[p]=hr_v[i]; }
  else if(i < 600000){ int j=i-300000; int p=atomicAdd(&cTR[tr_r[j]],1); scTR[p]=tr_c[j]; svTR[p]=tr_v[j]; }
  else if(i < 900000){ int j=i-600000; int p=atomicAdd(&cER[er_r[j]],1); scER[p]=er_c[j]; svER[p]=er_v[j]; }
  else if(i < 1500000){ int j=i-900000; int p=atomicAdd(&cAD[ad_r[j]],1); scAD[p]=ad_c[j]; svAD[p]=ad_v[j]; }
}

// ---------------- spmm's (CSR per-row, no atomics) ----------------
// rfwdb[r][off..off+300) bf16 = sum val * emb[col]
__global__ __launch_bounds__(256) void k_spmm_rel(
    const int* __restrict__ ptr, const int* __restrict__ scol, const float* __restrict__ sval,
    const unsigned short* __restrict__ embb, unsigned short* __restrict__ rfwdb, int off){
  int w = threadIdx.x >> 6, lane = threadIdx.x & 63;
  int r = blockIdx.x*2 + (w>>1);
  int half = w & 1;
  int elem = half*160 + 4*lane;
  bool act = (lane < 40) && (elem < 300);
  int b = ptr[r], e2 = ptr[r+1];
  float a0=0.f, a1=0.f, a2=0.f, a3=0.f;
  if(act){
    const unsigned short* base = embb + elem;
    int j = b;
    for(; j+4 <= e2; j += 4){
      int c0=scol[j], c1=scol[j+1], c2=scol[j+2], c3=scol[j+3];
      float v0=sval[j], v1=sval[j+1], v2=sval[j+2], v3=sval[j+3];
      uint2 x0 = *(const uint2*)(base + (size_t)c0*DP);
      uint2 x1 = *(const uint2*)(base + (size_t)c1*DP);
      uint2 x2 = *(const uint2*)(base + (size_t)c2*DP);
      uint2 x3 = *(const uint2*)(base + (size_t)c3*DP);
      a0 += v0*bf2f(x0.x&0xFFFF) + v1*bf2f(x1.x&0xFFFF) + v2*bf2f(x2.x&0xFFFF) + v3*bf2f(x3.x&0xFFFF);
      a1 += v0*bf2f(x0.x>>16)    + v1*bf2f(x1.x>>16)    + v2*bf2f(x2.x>>16)    + v3*bf2f(x3.x>>16);
      a2 += v0*bf2f(x0.y&0xFFFF) + v1*bf2f(x1.y&0xFFFF) + v2*bf2f(x2.y&0xFFFF) + v3*bf2f(x3.y&0xFFFF);
      a3 += v0*bf2f(x0.y>>16)    + v1*bf2f(x1.y>>16)    + v2*bf2f(x2.y>>16)    + v3*bf2f(x3.y>>16);
    }
    for(; j < e2; j++){
      int c = scol[j]; float v = sval[j];
      uint2 x = *(const uint2*)(base + (size_t)c*DP);
      a0 += v*bf2f(x.x&0xFFFF); a1 += v*bf2f(x.x>>16);
      a2 += v*bf2f(x.y&0xFFFF); a3 += v*bf2f(x.y>>16);
    }
    uint2 o;
    o.x = pack2(a0, a1);
    o.y = pack2(a2, a3);
    *(uint2*)&rfwdb[(size_t)r*640 + off + elem] = o;
  }
}

// gcn[e] = relu(sum val * x[col]); wave-per-row, 16B lanes (lanes 0..39)
__global__ __launch_bounds__(256) void k_spmm_adj(
    const int* __restrict__ ptr, const int* __restrict__ scol, const float* __restrict__ sval,
    const unsigned short* __restrict__ xin, unsigned short* __restrict__ out){
  int w = threadIdx.x >> 6, lane = threadIdx.x & 63;
  int e = blockIdx.x*4 + w;
  int b = ptr[e], en = ptr[e+1];
  if(lane < 40){
    float acc[8];
    #pragma unroll
    for(int i=0;i<8;i++) acc[i]=0.f;
    const unsigned short* base = xin + lane*8;
    for(int j=b; j<en; j++){
      int c = scol[j]; float v = sval[j];
      bf16x8 x = *(const bf16x8*)(base + (size_t)c*DP);
      #pragma unroll
      for(int i=0;i<8;i++) acc[i] += v * bf2f((unsigned short)x[i]);
    }
    bf16x8 o;
    #pragma unroll
    for(int i=0;i<8;i++) o[i] = (short)f2bf(fmaxf(acc[i], 0.f));
    *(bf16x8*)&out[(size_t)e*DP + lane*8] = o;
  }
}

// ---------------- MFMA GEMM with contiguous LDS staging ----------------
// C[E,320] = A[E,Kp] @ B + epilogue. BM=64 rows/block, 4 waves (n-split), 4m x 5n frags.
// A-tile = 40KB CONTIGUOUS global region -> staged to LDS via sequential uint4 copies
// (each wave-instruction = 1KB sequential: DRAM-friendly, each 128B line fetched once).
// Dense (Kp=960): 3 stages; stages 1,2 BUILD the nb-tile in LDS from er-CSR gathers of
// the L2-resident rfwdb (fuses spmm_er; nb never materialized in HBM).
// mode 0: out=bf16(c); mode 1: out=bf16(res+relu(c+bias)); mode 2: highway gate.
#define BM 64
__global__ __launch_bounds__(256,4) void k_gemm(
    const unsigned short* __restrict__ A1,     // [E, DP]
    const unsigned short* __restrict__ Bt,     // [320, Kp] (n-major, k-contiguous)
    int Kp,
    const int* __restrict__ erPtr, const int* __restrict__ erCol, const float* __restrict__ erVal,
    const unsigned short* __restrict__ rfwdb,  // [R,640] bf16
    const float* __restrict__ biasP,
    const unsigned short* __restrict__ gcn,
    const unsigned short* __restrict__ res,
    unsigned short* __restrict__ out,
    int mode){
  __shared__ unsigned short As[BM][DP];        // 40KB -> 4 blocks/CU
  int tid = threadIdx.x;
  int wave = tid>>6, lane = tid&63, quad = lane>>4, l16 = lane&15;
  int m0 = blockIdx.x * BM;
  unsigned short* flat = &As[0][0];

  f32x4 acc[4][5];
  #pragma unroll
  for(int mf=0; mf<4; mf++)
    #pragma unroll
    for(int nf=0; nf<5; nf++) acc[mf][nf] = (f32x4){0.f,0.f,0.f,0.f};

  int nstage = (Kp > DP) ? 3 : 1;
  for(int s=0; s<nstage; s++){
    if(s == 0){
      // contiguous 40KB copy: 256 thr x 10 x 16B
      const unsigned short* src = A1 + (size_t)m0*DP;
      #pragma unroll
      for(int i=0; i<10; i++){
        int off = (tid + i*256)*8;             // ushort index
        *(uint4*)(flat + off) = *(const uint4*)(src + off);
      }
    } else {
      // build nb cols [halfOff, halfOff+320) into LDS; wave handles 16 rows
      int halfOff = (s-1)*320;
      for(int rr=0; rr<16; rr++){
        int row = wave*16 + rr;
        int e = m0 + row;
        float a0[8], a1[8];
        #pragma unroll
        for(int i=0;i<8;i++){ a0[i]=0.f; a1[i]=0.f; }
        if(e < E_N && lane < 40){
          int jb = erPtr[e], je = erPtr[e+1];
          const unsigned short* gb = rfwdb + halfOff + lane*8;
          int j = jb;
          for(; j+2 <= je; j += 2){
            int c0=erCol[j], c1=erCol[j+1];
            float v0=erVal[j], v1=erVal[j+1];
            int p0=c0, p1=c1;
            if(c0 >= R_N){ p0 = c0-R_N; v0 = -v0; }
            if(c1 >= R_N){ p1 = c1-R_N; v1 = -v1; }
            bf16x8 x0 = *(const bf16x8*)(gb + (size_t)p0*640);
            bf16x8 x1 = *(const bf16x8*)(gb + (size_t)p1*640);
            #pragma unroll
            for(int i=0;i<8;i++){ a0[i] += v0*bf2f((unsigned short)x0[i]);
                                  a1[i] += v1*bf2f((unsigned short)x1[i]); }
          }
          if(j < je){
            int c=erCol[j]; float v=erVal[j];
            int p=c; if(c >= R_N){ p = c-R_N; v = -v; }
            bf16x8 x = *(const bf16x8*)(gb + (size_t)p*640);
            #pragma unroll
            for(int i=0;i<8;i++) a0[i] += v*bf2f((unsigned short)x[i]);
          }
        }
        if(lane < 40){
          bf16x8 o;
          #pragma unroll
          for(int i=0;i<8;i++) o[i] = (short)f2bf(a0[i]+a1[i]);
          *(bf16x8*)&As[row][lane*8] = o;
        }
      }
    }
    __syncthreads();
    int kb = s*DP;
    #pragma unroll 2
    for(int kk=0; kk<DP; kk+=32){
      bf16x8 af[4], bfr[5];
      #pragma unroll
      for(int mf=0; mf<4; mf++) af[mf] = *(const bf16x8*)&As[mf*16 + l16][kk + quad*8];
      #pragma unroll
      for(int nf=0; nf<5; nf++)
        bfr[nf] = *(const bf16x8*)(Bt + (size_t)(wave*80 + nf*16 + l16)*Kp + kb + kk + quad*8);
      #pragma unroll
      for(int mf=0; mf<4; mf++)
        #pragma unroll
        for(int nf=0; nf<5; nf++)
          acc[mf][nf] = __builtin_amdgcn_mfma_f32_16x16x32_bf16(af[mf], bfr[nf], acc[mf][nf], 0, 0, 0);
    }
    __syncthreads();
  }

  // epilogue: C/D layout col=lane&15, row=quad*4+i (verified)
  #pragma unroll
  for(int mf=0; mf<4; mf++){
    #pragma unroll
    for(int nf=0; nf<5; nf++){
      int col = wave*80 + nf*16 + l16;
      #pragma unroll
      for(int i=0; i<4; i++){
        int row = m0 + mf*16 + quad*4 + i;
        if(row >= E_N) continue;
        size_t idx = (size_t)row*DP + col;
        float c = acc[mf][nf][i];
        float o;
        if(mode == 0){
          o = c;
        } else if(mode == 1){
          o = bf2f(res[idx]) + fmaxf(c + biasP[col], 0.f);
        } else {
          float tg = 1.f / (1.f + expf(-(c + biasP[col])));
          o = tg * bf2f(gcn[idx]) + (1.f - tg) * bf2f(res[idx]);
        }
        out[idx] = f2bf(o);
      }
    }
  }
}

// ---------------- loss (640B-contiguous bf16x8 gathers) ----------------
__global__ __launch_bounds__(256) void k_dm(const unsigned short* __restrict__ node,
                                            const int* __restrict__ pl, const int* __restrict__ pr,
                                            float* __restrict__ Dm){
  int w = threadIdx.x >> 6, lane = threadIdx.x & 63;
  int t = blockIdx.x*4 + w;
  size_t lb = (size_t)pl[t]*DP, rb = (size_t)pr[t]*DP;
  float s = 0.f;
  if(lane < 40){
    bf16x8 L = *(const bf16x8*)&node[lb + lane*8];
    bf16x8 R = *(const bf16x8*)&node[rb + lane*8];
    #pragma unroll
    for(int i=0;i<8;i++) s += fabsf(bf2f((unsigned short)L[i]) - bf2f((unsigned short)R[i]));
  }
  #pragma unroll
  for(int off=32; off; off>>=1) s += __shfl_xor(s, off);
  if(lane==0) Dm[t] = s + 1.0f;   // + GAMMA
}

__global__ __launch_bounds__(256) void k_loss(const unsigned short* __restrict__ node,
                       const int* __restrict__ pl, const int* __restrict__ pr,
                       const int* __restrict__ nr, const int* __restrict__ nl,
                       const float* __restrict__ mask,
                       const float* __restrict__ Dm, float* __restrict__ part){
  int t = blockIdx.x;
  int w = threadIdx.x >> 6, lane = threadIdx.x & 63;
  __shared__ float wsum[4];
  bool act = lane < 40;
  size_t lb = (size_t)pl[t]*DP, rb = (size_t)pr[t]*DP;
  float lv[8], rv[8];
  #pragma unroll
  for(int i=0;i<8;i++){ lv[i]=0.f; rv[i]=0.f; }
  if(act){
    bf16x8 L = *(const bf16x8*)&node[lb + lane*8];
    bf16x8 R = *(const bf16x8*)&node[rb + lane*8];
    #pragma unroll
    for(int i=0;i<8;i++){ lv[i]=bf2f((unsigned short)L[i]); rv[i]=bf2f((unsigned short)R[i]); }
  }
  float dm = Dm[t];
  float local = 0.f;
  for(int k=w; k<K_N; k+=4){
    float s1=0.f, s2=0.f;
    if(act){
      size_t nrb = (size_t)nr[t*K_N+k]*DP, nlb = (size_t)nl[t*K_N+k]*DP;
      bf16x8 X = *(const bf16x8*)&node[nrb + lane*8];
      bf16x8 Y = *(const bf16x8*)&node[nlb + lane*8];
      #pragma unroll
      for(int i=0;i<8;i++){ s1 += fabsf(lv[i] - bf2f((unsigned short)X[i]));
                            s2 += fabsf(bf2f((unsigned short)Y[i]) - rv[i]); }
    }
    #pragma unroll
    for(int off=32; off; off>>=1){ s1 += __shfl_xor(s1, off); s2 += __shfl_xor(s2, off); }
    if(lane==0) local += (fmaxf(dm - s1, 0.f) + fmaxf(dm - s2, 0.f)) * mask[t*K_N+k];
  }
  if(lane==0) wsum[w] = local;
  __syncthreads();
  if(threadIdx.x==0) part[t] = wsum[0]+wsum[1]+wsum[2]+wsum[3];
}

__global__ void k_reduce(const float* part, float* out){
  __shared__ float s[256];
  int t = threadIdx.x;
  float a = 0.f;
  for(int i=t; i<T_N; i+=256) a += part[i];
  s[t] = a; __syncthreads();
  for(int off=128; off; off>>=1){ if(t<off) s[t]+=s[t+off]; __syncthreads(); }
  if(t==0) out[0] = s[0]*0.5f;
}

// ---------------- driver ----------------
extern "C" void kernel_launch(void* const* d_in, const int* in_sizes, int n_in,
                              void* d_out, int out_size, void* d_ws, size_t ws_size,
                              hipStream_t stream){
  const float* Wemb = (const float*)d_in[0];
  const float* KG   = (const float*)d_in[1];
  const float* BG   = (const float*)d_in[2];
  const float* W1   = (const float*)d_in[3];
  const float* W2   = (const float*)d_in[4];
  const float* DN   = (const float*)d_in[5];
  const float* BI   = (const float*)d_in[6];
  const int* HRr = (const int*)d_in[7];  const int* HRc = (const int*)d_in[8];  const float* HRv = (const float*)d_in[9];
  const int* TRr = (const int*)d_in[10]; const int* TRc = (const int*)d_in[11]; const float* TRv = (const float*)d_in[12];
  const int* ERr = (const int*)d_in[13]; const int* ERc = (const int*)d_in[14]; const float* ERv = (const float*)d_in[15];
  const int* ADr = (const int*)d_in[16]; const int* ADc = (const int*)d_in[17]; const float* ADv = (const float*)d_in[18];
  const int* PL = (const int*)d_in[19]; const int* PR = (const int*)d_in[20];
  const int* NR = (const int*)d_in[21]; const int* NL = (const int*)d_in[22];
  const float* MASK = (const float*)d_in[23];
  char* ws = (char*)d_ws;

  unsigned short* embb = (unsigned short*)(ws + OFF_EMBB);  // emb -> h -> hg1 -> node (in place)
  unsigned short* hwb  = (unsigned short*)(ws + OFF_HWB);
  unsigned short* gcnb = (unsigned short*)(ws + OFF_GCNB);
  unsigned short* rfwdb = (unsigned short*)(ws + OFF_RFWD);
  unsigned short* wtKG = (unsigned short*)(ws + OFF_WTKG);
  unsigned short* wtW1 = (unsigned short*)(ws + OFF_WTW1);
  unsigned short* wtW2 = (unsigned short*)(ws + OFF_WTW2);
  unsigned short* wtDN = (unsigned short*)(ws + OFF_WTDN);
  float* biasP = (float*)(ws + OFF_BIASP);
  float* bgP   = (float*)(ws + OFF_BGP);
  int* pHR = (int*)(ws + OFF_PTRHR); int* pTR = (int*)(ws + OFF_PTRTR);
  int* pER = (int*)(ws + OFF_PTRER); int* pAD = (int*)(ws + OFF_PTRADJ);
  int* cHR = (int*)(ws + OFF_CURHR); int* cTR = (int*)(ws + OFF_CURTR);
  int* cER = (int*)(ws + OFF_CURER); int* cAD = (int*)(ws + OFF_CURADJ);
  int* scHR = (int*)(ws + OFF_SCHR); float* svHR = (float*)(ws + OFF_SVHR);
  int* scTR = (int*)(ws + OFF_SCTR); float* svTR = (float*)(ws + OFF_SVTR);
  int* scER = (int*)(ws + OFF_SCER); float* svER = (float*)(ws + OFF_SVER);
  int* scAD = (int*)(ws + OFF_SCADJ); float* svAD = (float*)(ws + OFF_SVADJ);
  float* Dm   = (float*)(ws + OFF_DM);
  float* part = (float*)(ws + OFF_PART);
  int* bsum   = (int*)(ws + OFF_BSUM);

  (void)hipMemsetAsync(ws + OFF_CURHR, 0, SZ_CURALL, stream);
  (void)hipMemsetAsync(ws + OFF_RFWD, 0, 1280000, stream);   // rfwdb incl. pad cols

  k_prep_sq<<<dim3(320,3), 320, 0, stream>>>(KG, W1, W2, wtKG, wtW1, wtW2);
  k_prep_dense<<<320, 320, 0, stream>>>(DN, wtDN);
  k_prep_bias<<<1, 320, 0, stream>>>(BI, BG, biasP, bgP);
  k_normalize<<<E_N/4, 256, 0, stream>>>(Wemb, embb);

  k_count<<<5860, 256, 0, stream>>>(HRr, TRr, ERr, ADr, cHR, cTR, cER, cAD);
  k_scan_small<<<1, 1024, 0, stream>>>(cHR, cTR, pHR, pTR);
  k_scan_part<<<dim3(98,2), 1024, 0, stream>>>(cER, cAD, pER, pAD, bsum);
  k_scan_mid<<<1, 128, 0, stream>>>(bsum, pER, pAD);
  k_scan_add<<<dim3(98,2), 1024, 0, stream>>>(bsum, pER, pAD, cER, cAD);
  k_scatter<<<5860, 256, 0, stream>>>(HRr,HRc,HRv, TRr,TRc,TRv, ERr,ERc,ERv, ADr,ADc,ADv,
                                      cHR,cTR,cER,cAD, scHR,svHR, scTR,svTR, scER,svER, scAD,svAD);

  k_spmm_rel<<<R_N/2, 256, 0, stream>>>(pHR, scHR, svHR, embb, rfwdb, 0);
  k_spmm_rel<<<R_N/2, 256, 0, stream>>>(pTR, scTR, svTR, embb, rfwdb, 300);

  const int GB = (E_N + BM - 1) / BM;  // 1563
  // h = emb + relu([emb|nb] @ Dense + Bias)  (nb built in-LDS from er-CSR; in place)
  k_gemm<<<GB, 256, 0, stream>>>(embb, wtDN, KD, pER, scER, svER, rfwdb,
                                 biasP, nullptr, embb, embb, 1);
  // gcn1 = relu(spmm(adj, h@W1))
  k_gemm<<<GB, 256, 0, stream>>>(embb, wtW1, DP, nullptr, nullptr, nullptr, nullptr,
                                 nullptr, nullptr, nullptr, hwb, 0);
  k_spmm_adj<<<E_N/4, 256, 0, stream>>>(pAD, scAD, svAD, hwb, gcnb);
  // hg1 = highway(h, gcn1)  (in place)
  k_gemm<<<GB, 256, 0, stream>>>(embb, wtKG, DP, nullptr, nullptr, nullptr, nullptr,
                                 bgP, gcnb, embb, embb, 2);
  // gcn2 = relu(spmm(adj, hg1@W2))
  k_gemm<<<GB, 256, 0, stream>>>(embb, wtW2, DP, nullptr, nullptr, nullptr, nullptr,
                                 nullptr, nullptr, nullptr, hwb, 0);
  k_spmm_adj<<<E_N/4, 256, 0, stream>>>(pAD, scAD, svAD, hwb, gcnb);
  // node = highway(hg1, gcn2)  (in place)
  k_gemm<<<GB, 256, 0, stream>>>(embb, wtKG, DP, nullptr, nullptr, nullptr, nullptr,
                                 bgP, gcnb, embb, embb, 2);

  k_dm<<<T_N/4, 256, 0, stream>>>(embb, PL, PR, Dm);
  k_loss<<<T_N, 256, 0, stream>>>(embb, PL, PR, NR, NL, MASK, Dm, part);
  k_reduce<<<1, 256, 0, stream>>>(part, (float*)d_out);
}

// Round 4
// 1682.018 us; speedup vs baseline: 1.1603x; 1.1603x over previous
//
#include <hip/hip_runtime.h>
#include <math.h>

// Problem constants (fixed by setup_inputs)
#define E_N 100000
#define D_N 300
#define R_N 1000
#define T_N 10000
#define K_N 25
#define DP  320      // padded D (multiple of 32)
#define KD  960      // padded 3D

typedef __attribute__((ext_vector_type(8))) short bf16x8;
typedef __attribute__((ext_vector_type(4))) float f32x4;

__device__ __forceinline__ float bf2f(unsigned short h){
  union{ unsigned int u; float f; } c; c.u = ((unsigned int)h)<<16; return c.f;
}
__device__ __forceinline__ unsigned short f2bf(float f){
  union{ float f; unsigned int u; } c; c.f = f;
  unsigned int u = c.u + 0x7FFFu + ((c.u>>16)&1u);   // RNE
  return (unsigned short)(u>>16);
}
__device__ __forceinline__ unsigned int pack2(float lo, float hi){
  return ((unsigned int)f2bf(hi)<<16) | f2bf(lo);
}

// ---------------- workspace layout (bytes) ----------------
static constexpr size_t OFF_EMBB  = 0;                         // E*320*2 = 64MB (emb/h/hg1/node, in place)
static constexpr size_t OFF_HWB   = 64000000;                  // 64MB (h@W)
static constexpr size_t OFF_GCNB  = OFF_HWB + 64000000;        // 64MB
static constexpr size_t OFF_RFWD  = 192000000;                 // R*640*2 bf16 = 1.28MB
static constexpr size_t OFF_WTKG  = OFF_RFWD + 2400000;
static constexpr size_t OFF_WTW1  = OFF_WTKG + 204800;
static constexpr size_t OFF_WTW2  = OFF_WTW1 + 204800;
static constexpr size_t OFF_WTDN  = OFF_WTW2 + 204800;         // [320,960] bf16 transposed
static constexpr size_t OFF_BIASP = OFF_WTDN + 614400;
static constexpr size_t OFF_BGP   = OFF_BIASP + 1280;
static constexpr size_t OFF_PTRHR = OFF_BGP + 1280;
static constexpr size_t OFF_PTRTR = OFF_PTRHR + 4096;
static constexpr size_t OFF_PTRER = OFF_PTRTR + 4096;
static constexpr size_t OFF_PTRADJ= OFF_PTRER + 400896;
static constexpr size_t OFF_CURHR = OFF_PTRADJ + 400896;       // cursors contiguous: 1 memset
static constexpr size_t OFF_CURTR = OFF_CURHR + 4096;
static constexpr size_t OFF_CURER = OFF_CURTR + 4096;
static constexpr size_t OFF_CURADJ= OFF_CURER + 400896;
static constexpr size_t SZ_CURALL = 4096+4096+400896+400896;
static constexpr size_t OFF_SCHR  = OFF_CURADJ + 400896;
static constexpr size_t OFF_SVHR  = OFF_SCHR + 1200000;
static constexpr size_t OFF_SCTR  = OFF_SVHR + 1200000;
static constexpr size_t OFF_SVTR  = OFF_SCTR + 1200000;
static constexpr size_t OFF_SCER  = OFF_SVTR + 1200000;
static constexpr size_t OFF_SVER  = OFF_SCER + 1200000;
static constexpr size_t OFF_SCADJ = OFF_SVER + 1200000;
static constexpr size_t OFF_SVADJ = OFF_SCADJ + 2400000;
static constexpr size_t OFF_DM    = OFF_SVADJ + 2400000;
static constexpr size_t OFF_PART  = OFF_DM + 40000;
static constexpr size_t OFF_BSUM  = OFF_PART + 40000;          // 256 ints

// ---------------- weight prep ----------------
__global__ void k_prep_sq(const float* kg, const float* w1, const float* w2,
                          unsigned short* wtKG, unsigned short* wtW1, unsigned short* wtW2){
  int n = blockIdx.x, which = blockIdx.y, k = threadIdx.x;
  const float* src = which==0 ? kg : (which==1 ? w1 : w2);
  unsigned short* dst = which==0 ? wtKG : (which==1 ? wtW1 : wtW2);
  float v = (n < D_N && k < D_N) ? src[k*D_N + n] : 0.f;
  dst[(size_t)n*DP + k] = f2bf(v);
}

// DenseP_t[n][k]: k<300 -> Dense[k][n]; 320<=k<920 -> Dense[k-20][n]; else 0
__global__ void k_prep_dense(const float* dn, unsigned short* wt){
  int n = blockIdx.x, t = threadIdx.x;
  for(int k=t; k<KD; k+=320){
    int ko = (k < D_N) ? k : ((k >= DP && k < 920) ? k-20 : -1);
    float v = (n < D_N && ko >= 0) ? dn[(size_t)ko*D_N + n] : 0.f;
    wt[(size_t)n*KD + k] = f2bf(v);
  }
}

__global__ void k_prep_bias(const float* bias, const float* bg, float* biasP, float* bgP){
  int t = threadIdx.x;
  biasP[t] = (t < D_N) ? bias[t] : 0.f;
  bgP[t]   = (t < D_N) ? bg[t]   : 0.f;
}

// ---------------- emb normalize -> bf16 padded (wave-per-row, float4) ----------------
__global__ __launch_bounds__(256) void k_normalize(const float* __restrict__ w,
                                                   unsigned short* __restrict__ embb){
  int wv = threadIdx.x >> 6, lane = threadIdx.x & 63;
  int e = blockIdx.x*4 + wv;                      // grid = E/4
  const float4* row = (const float4*)(w + (size_t)e*D_N);   // 1200B rows, 16B aligned
  float4 x0 = row[lane];
  float4 x1 = make_float4(0.f,0.f,0.f,0.f);
  if(lane < 11) x1 = row[64 + lane];              // floats 256..299
  float s = x0.x*x0.x + x0.y*x0.y + x0.z*x0.z + x0.w*x0.w
          + x1.x*x1.x + x1.y*x1.y + x1.z*x1.z + x1.w*x1.w;
  #pragma unroll
  for(int off=32; off; off>>=1) s += __shfl_xor(s, off);
  float rn = rsqrtf(s);
  unsigned short* orow = embb + (size_t)e*DP;
  uint2 o0; o0.x = pack2(x0.x*rn, x0.y*rn); o0.y = pack2(x0.z*rn, x0.w*rn);
  *(uint2*)(orow + lane*4) = o0;
  if(lane < 16){
    uint2 o1 = make_uint2(0u,0u);
    if(lane < 11){ o1.x = pack2(x1.x*rn, x1.y*rn); o1.y = pack2(x1.z*rn, x1.w*rn); }
    *(uint2*)(orow + 256 + lane*4) = o1;          // cols 256..319 (incl. zero pad)
  }
}

// ---------------- CSR build (counting sort) ----------------
__global__ void k_count(const int* hr, const int* tr, const int* er, const int* ad,
                        int* cHR, int* cTR, int* cER, int* cAD){
  int i = blockIdx.x*256 + threadIdx.x;
  if(i < 300000)       atomicAdd(&cHR[hr[i]], 1);
  else if(i < 600000)  atomicAdd(&cTR[tr[i-300000]], 1);
  else if(i < 900000)  atomicAdd(&cER[er[i-600000]], 1);
  else if(i < 1500000) atomicAdd(&cAD[ad[i-900000]], 1);
}

__global__ void k_scan_small(int* cHR, int* cTR, int* pHR, int* pTR){
  __shared__ int s[1024];
  int t = threadIdx.x;
  for(int w=0; w<2; w++){
    int* cnt = w ? cTR : cHR; int* ptr = w ? pTR : pHR;
    int c = (t < R_N) ? cnt[t] : 0;
    s[t] = c; __syncthreads();
    for(int off=1; off<1024; off<<=1){
      int v = (t>=off) ? s[t-off] : 0; __syncthreads();
      s[t] += v; __syncthreads();
    }
    int excl = s[t] - c;
    if(t < R_N){ ptr[t] = excl; cnt[t] = excl; }
    if(t == R_N-1) ptr[R_N] = s[t];
    __syncthreads();
  }
}

__global__ void k_scan_part(const int* cER, const int* cAD, int* pER, int* pAD, int* bsum){
  int which = blockIdx.y;
  const int* cnt = which ? cAD : cER;
  int* ptr = which ? pAD : pER;
  __shared__ int s[1024];
  int g = blockIdx.x, t = threadIdx.x, i = g*1024 + t;
  int c = (i < E_N) ? cnt[i] : 0;
  s[t] = c; __syncthreads();
  for(int off=1; off<1024; off<<=1){
    int v = (t>=off) ? s[t-off] : 0; __syncthreads();
    s[t] += v; __syncthreads();
  }
  if(i < E_N) ptr[i] = s[t] - c;
  if(t == 1023) bsum[which*128 + g] = s[1023];
}

__global__ void k_scan_mid(int* bsum, int* pER, int* pAD){
  __shared__ int s[128];
  int t = threadIdx.x;
  for(int w=0; w<2; w++){
    int v = (t < 98) ? bsum[w*128 + t] : 0;
    s[t] = v; __syncthreads();
    for(int off=1; off<128; off<<=1){
      int u = (t>=off) ? s[t-off] : 0; __syncthreads();
      s[t] += u; __syncthreads();
    }
    if(t < 98) bsum[w*128 + t] = s[t] - v;
    if(t == 97){ int* p = w ? pAD : pER; p[E_N] = s[97]; }
    __syncthreads();
  }
}

__global__ void k_scan_add(const int* bsum, int* pER, int* pAD, int* curER, int* curAD){
  int which = blockIdx.y;
  int* ptr = which ? pAD : pER;
  int* cur = which ? curAD : curER;
  int g = blockIdx.x, i = g*1024 + threadIdx.x;
  if(i < E_N){ int v = ptr[i] + bsum[which*128 + g]; ptr[i] = v; cur[i] = v; }
}

__global__ void k_scatter(const int* hr_r, const int* hr_c, const float* hr_v,
                          const int* tr_r, const int* tr_c, const float* tr_v,
                          const int* er_r, const int* er_c, const float* er_v,
                          const int* ad_r, const int* ad_c, const float* ad_v,
                          int* cHR, int* cTR, int* cER, int* cAD,
                          int* scHR, float* svHR, int* scTR, float* svTR,
                          int* scER, float* svER, int* scAD, float* svAD){
  int i = blockIdx.x*256 + threadIdx.x;
  if(i < 300000){ int p=atomicAdd(&cHR[hr_r[i]],1); scHR[p]=hr_c[i]; svHR[p]=hr_v[i]; }
  else if(i < 600000){ int j=i-300000; int p=atomicAdd(&cTR[tr_r[j]],1); scTR[p]=tr_c[j]; svTR[p]=tr_v[j]; }
  else if(i < 900000){ int j=i-600000; int p=atomicAdd(&cER[er_r[j]],1); scER[p]=er_c[j]; svER[p]=er_v[j]; }
  else if(i < 1500000){ int j=i-900000; int p=atomicAdd(&cAD[ad_r[j]],1); scAD[p]=ad_c[j]; svAD[p]=ad_v[j]; }
}

// ---------------- spmm's (CSR per-row, no atomics) ----------------
// rfwdb[r][off..off+300) bf16 = sum val * emb[col]
__global__ __launch_bounds__(256) void k_spmm_rel(
    const int* __restrict__ ptr, const int* __restrict__ scol, const float* __restrict__ sval,
    const unsigned short* __restrict__ embb, unsigned short* __restrict__ rfwdb, int off){
  int w = threadIdx.x >> 6, lane = threadIdx.x & 63;
  int r = blockIdx.x*2 + (w>>1);
  int half = w & 1;
  int elem = half*160 + 4*lane;
  bool act = (lane < 40) && (elem < 300);
  int b = ptr[r], e2 = ptr[r+1];
  float a0=0.f, a1=0.f, a2=0.f, a3=0.f;
  if(act){
    const unsigned short* base = embb + elem;
    int j = b;
    for(; j+4 <= e2; j += 4){
      int c0=scol[j], c1=scol[j+1], c2=scol[j+2], c3=scol[j+3];
      float v0=sval[j], v1=sval[j+1], v2=sval[j+2], v3=sval[j+3];
      uint2 x0 = *(const uint2*)(base + (size_t)c0*DP);
      uint2 x1 = *(const uint2*)(base + (size_t)c1*DP);
      uint2 x2 = *(const uint2*)(base + (size_t)c2*DP);
      uint2 x3 = *(const uint2*)(base + (size_t)c3*DP);
      a0 += v0*bf2f(x0.x&0xFFFF) + v1*bf2f(x1.x&0xFFFF) + v2*bf2f(x2.x&0xFFFF) + v3*bf2f(x3.x&0xFFFF);
      a1 += v0*bf2f(x0.x>>16)    + v1*bf2f(x1.x>>16)    + v2*bf2f(x2.x>>16)    + v3*bf2f(x3.x>>16);
      a2 += v0*bf2f(x0.y&0xFFFF) + v1*bf2f(x1.y&0xFFFF) + v2*bf2f(x2.y&0xFFFF) + v3*bf2f(x3.y&0xFFFF);
      a3 += v0*bf2f(x0.y>>16)    + v1*bf2f(x1.y>>16)    + v2*bf2f(x2.y>>16)    + v3*bf2f(x3.y>>16);
    }
    for(; j < e2; j++){
      int c = scol[j]; float v = sval[j];
      uint2 x = *(const uint2*)(base + (size_t)c*DP);
      a0 += v*bf2f(x.x&0xFFFF); a1 += v*bf2f(x.x>>16);
      a2 += v*bf2f(x.y&0xFFFF); a3 += v*bf2f(x.y>>16);
    }
    uint2 o;
    o.x = pack2(a0, a1);
    o.y = pack2(a2, a3);
    *(uint2*)&rfwdb[(size_t)r*640 + off + elem] = o;
  }
}

// gcn[e] = relu(sum val * x[col]); wave-per-row, 16B lanes (lanes 0..39)
__global__ __launch_bounds__(256) void k_spmm_adj(
    const int* __restrict__ ptr, const int* __restrict__ scol, const float* __restrict__ sval,
    const unsigned short* __restrict__ xin, unsigned short* __restrict__ out){
  int w = threadIdx.x >> 6, lane = threadIdx.x & 63;
  int e = blockIdx.x*4 + w;
  int b = ptr[e], en = ptr[e+1];
  if(lane < 40){
    float acc[8];
    #pragma unroll
    for(int i=0;i<8;i++) acc[i]=0.f;
    const unsigned short* base = xin + lane*8;
    for(int j=b; j<en; j++){
      int c = scol[j]; float v = sval[j];
      bf16x8 x = *(const bf16x8*)(base + (size_t)c*DP);
      #pragma unroll
      for(int i=0;i<8;i++) acc[i] += v * bf2f((unsigned short)x[i]);
    }
    bf16x8 o;
    #pragma unroll
    for(int i=0;i<8;i++) o[i] = (short)f2bf(fmaxf(acc[i], 0.f));
    *(bf16x8*)&out[(size_t)e*DP + lane*8] = o;
  }
}

// ---------------- MFMA GEMM with contiguous LDS staging ----------------
// C[E,320] = A[E,Kp] @ B + epilogue. BM=64 rows/block, 4 waves (n-split), 4m x 5n frags.
// A-tile = 40KB CONTIGUOUS global region -> LDS via sequential uint4 copies.
// LDS layout XOR-swizzled at 16B-chunk granularity (chunk ^= row&7): kills the
// 16-way bank conflict of the 640B row stride while keeping 40KB (4 blocks/CU).
// Dense (Kp=960): 3 stages; stages 1,2 BUILD the nb-tile in LDS from er-CSR gathers of
// the L2-resident rfwdb (fuses spmm_er; nb never materialized in HBM).
// __launch_bounds__(256,2): rnd3's (256,4) capped regs at 64 -> acc spills ->
// 313MB scratch writes/dispatch. 80 acc regs require the 256-reg budget.
#define BM 64
__global__ __launch_bounds__(256,2) void k_gemm(
    const unsigned short* __restrict__ A1,     // [E, DP]
    const unsigned short* __restrict__ Bt,     // [320, Kp] (n-major, k-contiguous)
    int Kp,
    const int* __restrict__ erPtr, const int* __restrict__ erCol, const float* __restrict__ erVal,
    const unsigned short* __restrict__ rfwdb,  // [R,640] bf16
    const float* __restrict__ biasP,
    const unsigned short* __restrict__ gcn,
    const unsigned short* __restrict__ res,
    unsigned short* __restrict__ out,
    int mode){
  __shared__ unsigned short As[BM][DP];        // 40KB, XOR-swizzled chunks
  int tid = threadIdx.x;
  int wave = tid>>6, lane = tid&63, quad = lane>>4, l16 = lane&15;
  int m0 = blockIdx.x * BM;

  f32x4 acc[4][5];
  #pragma unroll
  for(int mf=0; mf<4; mf++)
    #pragma unroll
    for(int nf=0; nf<5; nf++) acc[mf][nf] = (f32x4){0.f,0.f,0.f,0.f};

  int nstage = (Kp > DP) ? 3 : 1;
  for(int s=0; s<nstage; s++){
    if(s == 0){
      // contiguous 40KB copy: 256 thr x 10 x 16B, swizzled LDS placement
      const unsigned short* src = A1 + (size_t)m0*DP;
      #pragma unroll
      for(int i=0; i<10; i++){
        int idx = tid + i*256;                 // 16B chunk id, 0..2559
        int row = idx / 40, colc = idx % 40;
        int pc = colc ^ (row & 7);
        *(uint4*)&As[row][pc*8] = *(const uint4*)(src + idx*8);
      }
    } else {
      // build nb cols [halfOff, halfOff+320) into LDS; wave handles 16 rows
      int halfOff = (s-1)*320;
      for(int rr=0; rr<16; rr++){
        int row = wave*16 + rr;
        int e = m0 + row;
        float a0[8], a1[8];
        #pragma unroll
        for(int i=0;i<8;i++){ a0[i]=0.f; a1[i]=0.f; }
        if(e < E_N && lane < 40){
          int jb = erPtr[e], je = erPtr[e+1];
          const unsigned short* gb = rfwdb + halfOff + lane*8;
          int j = jb;
          for(; j+2 <= je; j += 2){
            int c0=erCol[j], c1=erCol[j+1];
            float v0=erVal[j], v1=erVal[j+1];
            int p0=c0, p1=c1;
            if(c0 >= R_N){ p0 = c0-R_N; v0 = -v0; }
            if(c1 >= R_N){ p1 = c1-R_N; v1 = -v1; }
            bf16x8 x0 = *(const bf16x8*)(gb + (size_t)p0*640);
            bf16x8 x1 = *(const bf16x8*)(gb + (size_t)p1*640);
            #pragma unroll
            for(int i=0;i<8;i++){ a0[i] += v0*bf2f((unsigned short)x0[i]);
                                  a1[i] += v1*bf2f((unsigned short)x1[i]); }
          }
          if(j < je){
            int c=erCol[j]; float v=erVal[j];
            int p=c; if(c >= R_N){ p = c-R_N; v = -v; }
            bf16x8 x = *(const bf16x8*)(gb + (size_t)p*640);
            #pragma unroll
            for(int i=0;i<8;i++) a0[i] += v*bf2f((unsigned short)x[i]);
          }
        }
        if(lane < 40){
          bf16x8 o;
          #pragma unroll
          for(int i=0;i<8;i++) o[i] = (short)f2bf(a0[i]+a1[i]);
          int pc = lane ^ (row & 7);
          *(bf16x8*)&As[row][pc*8] = o;
        }
      }
    }
    __syncthreads();
    int kb = s*DP;
    #pragma unroll 2
    for(int kk=0; kk<DP; kk+=32){
      bf16x8 af[4], bfr[5];
      #pragma unroll
      for(int mf=0; mf<4; mf++){
        int pc = ((kk>>3) + quad) ^ (l16 & 7);   // row = mf*16+l16, row&7 == l16&7
        af[mf] = *(const bf16x8*)&As[mf*16 + l16][pc*8];
      }
      #pragma unroll
      for(int nf=0; nf<5; nf++)
        bfr[nf] = *(const bf16x8*)(Bt + (size_t)(wave*80 + nf*16 + l16)*Kp + kb + kk + quad*8);
      #pragma unroll
      for(int mf=0; mf<4; mf++)
        #pragma unroll
        for(int nf=0; nf<5; nf++)
          acc[mf][nf] = __builtin_amdgcn_mfma_f32_16x16x32_bf16(af[mf], bfr[nf], acc[mf][nf], 0, 0, 0);
    }
    __syncthreads();
  }

  // epilogue: C/D layout col=lane&15, row=quad*4+i (verified)
  #pragma unroll
  for(int mf=0; mf<4; mf++){
    #pragma unroll
    for(int nf=0; nf<5; nf++){
      int col = wave*80 + nf*16 + l16;
      #pragma unroll
      for(int i=0; i<4; i++){
        int row = m0 + mf*16 + quad*4 + i;
        if(row >= E_N) continue;
        size_t idx = (size_t)row*DP + col;
        float c = acc[mf][nf][i];
        float o;
        if(mode == 0){
          o = c;
        } else if(mode == 1){
          o = bf2f(res[idx]) + fmaxf(c + biasP[col], 0.f);
        } else {
          float tg = 1.f / (1.f + expf(-(c + biasP[col])));
          o = tg * bf2f(gcn[idx]) + (1.f - tg) * bf2f(res[idx]);
        }
        out[idx] = f2bf(o);
      }
    }
  }
}

// ---------------- loss (640B-contiguous bf16x8 gathers) ----------------
__global__ __launch_bounds__(256) void k_dm(const unsigned short* __restrict__ node,
                                            const int* __restrict__ pl, const int* __restrict__ pr,
                                            float* __restrict__ Dm){
  int w = threadIdx.x >> 6, lane = threadIdx.x & 63;
  int t = blockIdx.x*4 + w;
  size_t lb = (size_t)pl[t]*DP, rb = (size_t)pr[t]*DP;
  float s = 0.f;
  if(lane < 40){
    bf16x8 L = *(const bf16x8*)&node[lb + lane*8];
    bf16x8 R = *(const bf16x8*)&node[rb + lane*8];
    #pragma unroll
    for(int i=0;i<8;i++) s += fabsf(bf2f((unsigned short)L[i]) - bf2f((unsigned short)R[i]));
  }
  #pragma unroll
  for(int off=32; off; off>>=1) s += __shfl_xor(s, off);
  if(lane==0) Dm[t] = s + 1.0f;   // + GAMMA
}

__global__ __launch_bounds__(256) void k_loss(const unsigned short* __restrict__ node,
                       const int* __restrict__ pl, const int* __restrict__ pr,
                       const int* __restrict__ nr, const int* __restrict__ nl,
                       const float* __restrict__ mask,
                       const float* __restrict__ Dm, float* __restrict__ part){
  int t = blockIdx.x;
  int w = threadIdx.x >> 6, lane = threadIdx.x & 63;
  __shared__ float wsum[4];
  bool act = lane < 40;
  size_t lb = (size_t)pl[t]*DP, rb = (size_t)pr[t]*DP;
  float lv[8], rv[8];
  #pragma unroll
  for(int i=0;i<8;i++){ lv[i]=0.f; rv[i]=0.f; }
  if(act){
    bf16x8 L = *(const bf16x8*)&node[lb + lane*8];
    bf16x8 R = *(const bf16x8*)&node[rb + lane*8];
    #pragma unroll
    for(int i=0;i<8;i++){ lv[i]=bf2f((unsigned short)L[i]); rv[i]=bf2f((unsigned short)R[i]); }
  }
  float dm = Dm[t];
  float local = 0.f;
  for(int k=w; k<K_N; k+=4){
    float s1=0.f, s2=0.f;
    if(act){
      size_t nrb = (size_t)nr[t*K_N+k]*DP, nlb = (size_t)nl[t*K_N+k]*DP;
      bf16x8 X = *(const bf16x8*)&node[nrb + lane*8];
      bf16x8 Y = *(const bf16x8*)&node[nlb + lane*8];
      #pragma unroll
      for(int i=0;i<8;i++){ s1 += fabsf(lv[i] - bf2f((unsigned short)X[i]));
                            s2 += fabsf(bf2f((unsigned short)Y[i]) - rv[i]); }
    }
    #pragma unroll
    for(int off=32; off; off>>=1){ s1 += __shfl_xor(s1, off); s2 += __shfl_xor(s2, off); }
    if(lane==0) local += (fmaxf(dm - s1, 0.f) + fmaxf(dm - s2, 0.f)) * mask[t*K_N+k];
  }
  if(lane==0) wsum[w] = local;
  __syncthreads();
  if(threadIdx.x==0) part[t] = wsum[0]+wsum[1]+wsum[2]+wsum[3];
}

__global__ void k_reduce(const float* part, float* out){
  __shared__ float s[256];
  int t = threadIdx.x;
  float a = 0.f;
  for(int i=t; i<T_N; i+=256) a += part[i];
  s[t] = a; __syncthreads();
  for(int off=128; off; off>>=1){ if(t<off) s[t]+=s[t+off]; __syncthreads(); }
  if(t==0) out[0] = s[0]*0.5f;
}

// ---------------- driver ----------------
extern "C" void kernel_launch(void* const* d_in, const int* in_sizes, int n_in,
                              void* d_out, int out_size, void* d_ws, size_t ws_size,
                              hipStream_t stream){
  const float* Wemb = (const float*)d_in[0];
  const float* KG   = (const float*)d_in[1];
  const float* BG   = (const float*)d_in[2];
  const float* W1   = (const float*)d_in[3];
  const float* W2   = (const float*)d_in[4];
  const float* DN   = (const float*)d_in[5];
  const float* BI   = (const float*)d_in[6];
  const int* HRr = (const int*)d_in[7];  const int* HRc = (const int*)d_in[8];  const float* HRv = (const float*)d_in[9];
  const int* TRr = (const int*)d_in[10]; const int* TRc = (const int*)d_in[11]; const float* TRv = (const float*)d_in[12];
  const int* ERr = (const int*)d_in[13]; const int* ERc = (const int*)d_in[14]; const float* ERv = (const float*)d_in[15];
  const int* ADr = (const int*)d_in[16]; const int* ADc = (const int*)d_in[17]; const float* ADv = (const float*)d_in[18];
  const int* PL = (const int*)d_in[19]; const int* PR = (const int*)d_in[20];
  const int* NR = (const int*)d_in[21]; const int* NL = (const int*)d_in[22];
  const float* MASK = (const float*)d_in[23];
  char* ws = (char*)d_ws;

  unsigned short* embb = (unsigned short*)(ws + OFF_EMBB);  // emb -> h -> hg1 -> node (in place)
  unsigned short* hwb  = (unsigned short*)(ws + OFF_HWB);
  unsigned short* gcnb = (unsigned short*)(ws + OFF_GCNB);
  unsigned short* rfwdb = (unsigned short*)(ws + OFF_RFWD);
  unsigned short* wtKG = (unsigned short*)(ws + OFF_WTKG);
  unsigned short* wtW1 = (unsigned short*)(ws + OFF_WTW1);
  unsigned short* wtW2 = (unsigned short*)(ws + OFF_WTW2);
  unsigned short* wtDN = (unsigned short*)(ws + OFF_WTDN);
  float* biasP = (float*)(ws + OFF_BIASP);
  float* bgP   = (float*)(ws + OFF_BGP);
  int* pHR = (int*)(ws + OFF_PTRHR); int* pTR = (int*)(ws + OFF_PTRTR);
  int* pER = (int*)(ws + OFF_PTRER); int* pAD = (int*)(ws + OFF_PTRADJ);
  int* cHR = (int*)(ws + OFF_CURHR); int* cTR = (int*)(ws + OFF_CURTR);
  int* cER = (int*)(ws + OFF_CURER); int* cAD = (int*)(ws + OFF_CURADJ);
  int* scHR = (int*)(ws + OFF_SCHR); float* svHR = (float*)(ws + OFF_SVHR);
  int* scTR = (int*)(ws + OFF_SCTR); float* svTR = (float*)(ws + OFF_SVTR);
  int* scER = (int*)(ws + OFF_SCER); float* svER = (float*)(ws + OFF_SVER);
  int* scAD = (int*)(ws + OFF_SCADJ); float* svAD = (float*)(ws + OFF_SVADJ);
  float* Dm   = (float*)(ws + OFF_DM);
  float* part = (float*)(ws + OFF_PART);
  int* bsum   = (int*)(ws + OFF_BSUM);

  (void)hipMemsetAsync(ws + OFF_CURHR, 0, SZ_CURALL, stream);
  (void)hipMemsetAsync(ws + OFF_RFWD, 0, 1280000, stream);   // rfwdb incl. pad cols

  k_prep_sq<<<dim3(320,3), 320, 0, stream>>>(KG, W1, W2, wtKG, wtW1, wtW2);
  k_prep_dense<<<320, 320, 0, stream>>>(DN, wtDN);
  k_prep_bias<<<1, 320, 0, stream>>>(BI, BG, biasP, bgP);
  k_normalize<<<E_N/4, 256, 0, stream>>>(Wemb, embb);

  k_count<<<5860, 256, 0, stream>>>(HRr, TRr, ERr, ADr, cHR, cTR, cER, cAD);
  k_scan_small<<<1, 1024, 0, stream>>>(cHR, cTR, pHR, pTR);
  k_scan_part<<<dim3(98,2), 1024, 0, stream>>>(cER, cAD, pER, pAD, bsum);
  k_scan_mid<<<1, 128, 0, stream>>>(bsum, pER, pAD);
  k_scan_add<<<dim3(98,2), 1024, 0, stream>>>(bsum, pER, pAD, cER, cAD);
  k_scatter<<<5860, 256, 0, stream>>>(HRr,HRc,HRv, TRr,TRc,TRv, ERr,ERc,ERv, ADr,ADc,ADv,
                                      cHR,cTR,cER,cAD, scHR,svHR, scTR,svTR, scER,svER, scAD,svAD);

  k_spmm_rel<<<R_N/2, 256, 0, stream>>>(pHR, scHR, svHR, embb, rfwdb, 0);
  k_spmm_rel<<<R_N/2, 256, 0, stream>>>(pTR, scTR, svTR, embb, rfwdb, 300);

  const int GB = (E_N + BM - 1) / BM;  // 1563
  // h = emb + relu([emb|nb] @ Dense + Bias)  (nb built in-LDS from er-CSR; in place)
  k_gemm<<<GB, 256, 0, stream>>>(embb, wtDN, KD, pER, scER, svER, rfwdb,
                                 biasP, nullptr, embb, embb, 1);
  // gcn1 = relu(spmm(adj, h@W1))
  k_gemm<<<GB, 256, 0, stream>>>(embb, wtW1, DP, nullptr, nullptr, nullptr, nullptr,
                                 nullptr, nullptr, nullptr, hwb, 0);
  k_spmm_adj<<<E_N/4, 256, 0, stream>>>(pAD, scAD, svAD, hwb, gcnb);
  // hg1 = highway(h, gcn1)  (in place)
  k_gemm<<<GB, 256, 0, stream>>>(embb, wtKG, DP, nullptr, nullptr, nullptr, nullptr,
                                 bgP, gcnb, embb, embb, 2);
  // gcn2 = relu(spmm(adj, hg1@W2))
  k_gemm<<<GB, 256, 0, stream>>>(embb, wtW2, DP, nullptr, nullptr, nullptr, nullptr,
                                 nullptr, nullptr, nullptr, hwb, 0);
  k_spmm_adj<<<E_N/4, 256, 0, stream>>>(pAD, scAD, svAD, hwb, gcnb);
  // node = highway(hg1, gcn2)  (in place)
  k_gemm<<<GB, 256, 0, stream>>>(embb, wtKG, DP, nullptr, nullptr, nullptr, nullptr,
                                 bgP, gcnb, embb, embb, 2);

  k_dm<<<T_N/4, 256, 0, stream>>>(embb, PL, PR, Dm);
  k_loss<<<T_N, 256, 0, stream>>>(embb, PL, PR, NR, NL, MASK, Dm, part);
  k_reduce<<<1, 256, 0, stream>>>(part, (float*)d_out);
}